// Round 11
// baseline (944.034 us; speedup 1.0000x reference)
//
#include <hip/hip_runtime.h>
#include <cstdint>
#include <cstddef>

constexpr int BB  = 32;
constexpr int TT  = 384;
constexpr int MM  = 1536;
constexpr int W32 = MM / 32;       // 48 canonical bit-windows
constexpr float NEGV = -1.0e7f;
constexpr int RING  = 40;          // LDS ring columns (61,440 B)
constexpr int DPRE  = 7;           // global->LDS prefetch distance (columns)
constexpr int STEPS = 1568;        // 1536 + 31 (pair skew) rounded to 49 windows
constexpr int WRD   = 49;          // skewed bit words per row

// workspace: skw-bits[BB][WRD][TT] (canonical in-place after repack) + A[BB][512]
constexpr size_t WS_BITS_SZ = (size_t)BB * WRD * TT * 4;   // 2,408,448
constexpr size_t WS_A_OFF   = WS_BITS_SZ;

typedef const __attribute__((address_space(1))) uint32_t glb_u32;
typedef __attribute__((address_space(3))) uint32_t lds_u32;

// ---------------- tiled transpose: in [b][t][j] -> outT [b][j][t] (proven) ----------------
__global__ __launch_bounds__(256) void mas_transpose(
    const float* __restrict__ in, float* __restrict__ outT)
{
  __shared__ float tile[32][33];
  const int b  = blockIdx.z;
  const int t0 = blockIdx.y * 32, j0 = blockIdx.x * 32;
  const int tx = threadIdx.x, ty = threadIdx.y;
  const float* ip = in  + (size_t)b * TT * MM;
  float*       op = outT + (size_t)b * TT * MM;
#pragma unroll
  for (int i = 0; i < 4; ++i)
    tile[ty + 8 * i][tx] = ip[(size_t)(t0 + ty + 8 * i) * MM + j0 + tx];
  __syncthreads();
#pragma unroll
  for (int i = 0; i < 4; ++i)
    op[(size_t)(j0 + ty + 8 * i) * TT + t0 + tx] = tile[tx][ty + 8 * i];
}

// ---------------- systolic DP + repack + backtrack: 1 wave per sample ----------------
// Lane k (pair p=k>>1) owns rows rb..rb+5, rb = 12p + 6(k&1). At step s it
// processes column c = s - p. Boundary Q[rb-1][c-1]: odd lanes <- pair-mate's
// qp[5] shfl'd 1 step ago (sh1); even lanes <- previous pair's qp[5] shfl'd
// 2 steps ago (sh2)  => the shfl is OFF the serial critical chain.
// Identical FP DAG to the reference (x + fmaxf(stay, adv) per cell).
__global__ __launch_bounds__(64, 1) void mas_main(
    const float* __restrict__ Tq, const float* __restrict__ mk0,
    uint32_t* __restrict__ skw, int* __restrict__ A)
{
  __shared__ float ring[RING * TT];               // 61,440 B
  const int b = blockIdx.x;
  const int k = threadIdx.x;
  const int p = k >> 1;
  const float* mk = mk0 + (size_t)b * TT * MM;
  uint32_t* bitsS = skw + (size_t)b * WRD * TT;   // [word][row]
  int* Ab = A + b * 512;

  // ---- lengths from mask (proven) ----
  float ts = 0.f, ms = 0.f;
  for (int t = k; t < TT; t += 64) ts += mk[(size_t)t * MM];
  for (int j = k; j < MM; j += 64) ms += mk[j];
#pragma unroll
  for (int off = 32; off >= 1; off >>= 1) {
    ts += __shfl_xor(ts, off);
    ms += __shfl_xor(ms, off);
  }
  const int t_len = (int)ts;
  const int m_len = (int)ms;
  for (int t = k; t <= TT; t += 64) Ab[t] = (t >= t_len) ? m_len : 0;

  const float* Tp = Tq + (size_t)b * TT * MM;     // [j][t]
  const int rb = 12 * p + 6 * (k & 1);            // first row owned
  float    qp[6];
  uint32_t bacc[6];
#pragma unroll
  for (int i = 0; i < 6; ++i) { qp[i] = NEGV; bacc[i] = 0u; }
  float sh1 = NEGV, sh2 = NEGV;                   // shfl pipeline (1 / 2 steps old)

  // ---- prologue: stream columns 0..DPRE-1 into the LDS ring ----
  for (int cc = 0; cc < DPRE; ++cc) {
    const float* g = Tp + (size_t)cc * TT;
    __builtin_amdgcn_global_load_lds((glb_u32*)(g + 4 * k),
                                     (lds_u32*)&ring[cc * TT], 16, 0, 0);
    if (k < 32)
      __builtin_amdgcn_global_load_lds((glb_u32*)(g + 256 + 4 * k),
                                       (lds_u32*)&ring[cc * TT + 256], 16, 0, 0);
  }
  asm volatile("s_waitcnt vmcnt(12)" ::: "memory");   // col 0 resident

  float2 bA[3], bB[3];
  {  // initial read: step-0 data (col -p; garbage for p>0 — those lanes inactive)
    int c0 = -p; if (c0 < 0) c0 += RING;
    const float* q0 = &ring[c0 * TT + rb];
    bA[0] = *(const float2*)q0; bA[1] = *(const float2*)(q0 + 2); bA[2] = *(const float2*)(q0 + 4);
  }

  int smod = 0;

#define SYS_STEP(S, CUR, NXT) do {                                               \
    {  /* global prefetch column S+DPRE */                                       \
      const int cp = (S) + DPRE;                                                 \
      int cpm = smod + DPRE; if (cpm >= RING) cpm -= RING;                       \
      if (cp < MM) {                                                             \
        const float* g = Tp + (size_t)cp * TT;                                   \
        __builtin_amdgcn_global_load_lds((glb_u32*)(g + 4 * k),                  \
                                         (lds_u32*)&ring[cpm * TT], 16, 0, 0);   \
        if (k < 32)                                                              \
          __builtin_amdgcn_global_load_lds((glb_u32*)(g + 256 + 4 * k),          \
                                   (lds_u32*)&ring[cpm * TT + 256], 16, 0, 0);   \
      }                                                                          \
    }                                                                            \
    asm volatile("s_waitcnt vmcnt(12)" ::: "memory"); /* step S+1 data resident */\
    {  /* ds prefetch step S+1 data (col S+1-p) into NXT */                      \
      int nm = smod + 1; if (nm >= RING) nm -= RING;                             \
      int cn = nm - p; if (cn < 0) cn += RING;                                   \
      const float* np = &ring[cn * TT + rb];                                     \
      NXT[0] = *(const float2*)np;                                               \
      NXT[1] = *(const float2*)(np + 2);                                         \
      NXT[2] = *(const float2*)(np + 4);                                         \
    }                                                                            \
    {  /* consume CUR = step S data (col c = S - p) */                           \
      const int c = (S) - p;                                                     \
      if ((unsigned)c < (unsigned)MM) {                                          \
        const float Bv = (k == 0) ? ((c == 0) ? 0.0f : NEGV)                     \
                                  : ((k & 1) ? sh1 : sh2);                       \
        const uint32_t mbit = 1u << ((S) & 31);                                  \
        const float x0 = CUR[0].x, x1 = CUR[0].y, x2 = CUR[1].x;                 \
        const float x3 = CUR[1].y, x4 = CUR[2].x, x5 = CUR[2].y;                 \
        _Pragma("unroll")                                                        \
        for (int i = 5; i >= 0; --i) {                                           \
          const float stay = qp[i];                                              \
          const float adv  = i ? qp[i - 1] : Bv;                                 \
          const float x = (i == 0) ? x0 : (i == 1) ? x1 : (i == 2) ? x2          \
                        : (i == 3) ? x3 : (i == 4) ? x4 : x5;                    \
          if (stay < adv) bacc[i] |= mbit;                                       \
          qp[i] = x + fmaxf(stay, adv);                                          \
        }                                                                        \
      }                                                                          \
    }                                                                            \
    sh2 = sh1;                                                                   \
    sh1 = __shfl_up(qp[5], 1);                                                   \
    if (((S) & 31) == 31) {  /* uniform flush: skewed word S>>5 */               \
      const int widx = (S) >> 5;                                                 \
      _Pragma("unroll")                                                          \
      for (int i = 0; i < 6; ++i) {                                              \
        bitsS[widx * TT + rb + i] = bacc[i]; bacc[i] = 0u;                       \
      }                                                                          \
    }                                                                            \
    ++smod; if (smod >= RING) smod = 0;                                          \
  } while (0)

#pragma unroll 1
  for (int s = 0; s < STEPS; s += 2) {
    SYS_STEP(s,     bA, bB);
    SYS_STEP(s + 1, bB, bA);
  }
#undef SYS_STEP

  asm volatile("s_waitcnt vmcnt(0)" ::: "memory");   // skewed bit stores done

  // ---- repack: skewed -> canonical, in place (funnel shift by p per row) ----
#pragma unroll
  for (int i = 0; i < 6; ++i) {
    const int r = rb + i;
    uint32_t Aw = bitsS[r];                       // skewed word 0
    for (int w = 0; w < W32; ++w) {
      const uint32_t Bw = bitsS[(w + 1) * TT + r];
      bitsS[w * TT + r] = (uint32_t)((((uint64_t)Bw << 32) | Aw) >> p);
      Aw = Bw;
    }
  }
  asm volatile("s_waitcnt vmcnt(0)" ::: "memory");   // canonical stores done

  // ---- backtrack (R3/R6-proven, verbatim): lane L caches row (t_top-L)'s word ----
  int t = t_len - 1;
  int jj = m_len - 1;
  if (t <= 0 || jj < 1) return;
  int t_top = t;
  int w_cur = jj >> 5;
  uint32_t word;
  { const int row = t_top - k; word = (row >= 0) ? bitsS[w_cur * TT + row] : 0u; }

  for (int guard = 0; guard < 4096; ++guard) {
    const uint32_t cur = __shfl(word, t_top - t);
    const int bpos = jj & 31;
    uint32_t m = cur & ((bpos == 31) ? 0xffffffffu : ((2u << bpos) - 1u));
    if (w_cur == 0) m &= ~1u;
    if (m == 0u) {
      if (w_cur == 0) break;
      --w_cur; jj = (w_cur << 5) | 31;
      t_top = t;
      const int row = t_top - k;
      word = (row >= 0) ? bitsS[w_cur * TT + row] : 0u;
      continue;
    }
    const int pb = 31 - __builtin_clz(m);
    jj = (w_cur << 5) | pb;
    if (k == 0) Ab[t] = jj;
    --t; --jj;
    if (t <= 0 || jj < 1) break;
    const int wn = jj >> 5;
    if (wn != w_cur || (t_top - t) > 63) {
      w_cur = wn; t_top = t;
      const int row = t_top - k;
      word = (row >= 0) ? bitsS[w_cur * TT + row] : 0u;
    }
  }
}

// ---------------- dense fill (proven): overwrites Tq remnants in d_out ----------------
__global__ __launch_bounds__(256) void mas_fill(
    const int* __restrict__ A, float* __restrict__ out)
{
  const int idx = blockIdx.x * 256 + threadIdx.x;   // over B*T*(M/4)
  const int nj4 = MM / 4;
  const int j4 = (idx % nj4) * 4;
  const int t  = (idx / nj4) % TT;
  const int b  = idx / (nj4 * TT);
  const int a  = A[b * 512 + t];
  const int e  = A[b * 512 + t + 1];
  float4 v;
  v.x = (j4 + 0 >= a && j4 + 0 < e) ? 1.0f : 0.0f;
  v.y = (j4 + 1 >= a && j4 + 1 < e) ? 1.0f : 0.0f;
  v.z = (j4 + 2 >= a && j4 + 2 < e) ? 1.0f : 0.0f;
  v.w = (j4 + 3 >= a && j4 + 3 < e) ? 1.0f : 0.0f;
  reinterpret_cast<float4*>(out)[idx] = v;
}

extern "C" void kernel_launch(void* const* d_in, const int* in_sizes, int n_in,
                              void* d_out, int out_size, void* d_ws, size_t ws_size,
                              hipStream_t stream) {
  const float* log_p = (const float*)d_in[0];
  const float* maskp = (const float*)d_in[1];
  float* out = (float*)d_out;
  uint32_t* skw = (uint32_t*)d_ws;
  int* A = (int*)((char*)d_ws + WS_A_OFF);
  float* Tq = out;   // d_out holds the transpose until mas_fill overwrites it

  mas_transpose<<<dim3(MM / 32, TT / 32, BB), dim3(32, 8), 0, stream>>>(log_p, Tq);
  mas_main<<<BB, 64, 0, stream>>>(Tq, maskp, skw, A);
  mas_fill<<<(BB * TT * (MM / 4)) / 256, 256, 0, stream>>>(A, out);
}